// Round 2
// baseline (108.893 us; speedup 1.0000x reference)
//
#include <hip/hip_runtime.h>
#include <hip/hip_bf16.h>
#include <math.h>

#define N_TOK 4096
#define M_TOK 1024
#define DMODEL 512
#define NHEAD 8
#define DHEAD 64

typedef __attribute__((ext_vector_type(8))) short short8;
typedef __attribute__((ext_vector_type(4))) float f32x4;
typedef __attribute__((ext_vector_type(4))) float float4v;

static __device__ __forceinline__ short f2bf(float f) {
    union { float f; unsigned u; } v; v.f = f;
    unsigned r = v.u + 0x7fffu + ((v.u >> 16) & 1u);
    return (short)(r >> 16);
}

// ---------------------------------------------------------------------------
// Pack: fp32 -> bf16. Activations row-major; ALL weights stored TRANSPOSED
// B^T[n][k] so GEMM B-staging is a plain vector copy.
//   wq/wk/wv: B^T[n=h*64+e][k=d] = W[h][d][e]
//   wo:       B^T[n=j][k=d]      = Wout[d][j]
// ---------------------------------------------------------------------------
__global__ void pack_kernel(const float* __restrict__ xv, const float* __restrict__ xt,
                            const float* __restrict__ wq, const float* __restrict__ wk,
                            const float* __restrict__ wv, const float* __restrict__ wo,
                            short* __restrict__ xvb, short* __restrict__ xtb,
                            short* __restrict__ wqb, short* __restrict__ wkb,
                            short* __restrict__ wvb, short* __restrict__ wob) {
    int idx = blockIdx.x * 256 + threadIdx.x;
    int stride = gridDim.x * 256;
    const int CXV = N_TOK * DMODEL / 8;
    const int CXT = M_TOK * DMODEL / 8;
    const int NW  = DMODEL * DMODEL;
    for (int c = idx; c < CXV; c += stride) {
        float4v f0 = *(const float4v*)&xv[c * 8];
        float4v f1 = *(const float4v*)&xv[c * 8 + 4];
        short8 o;
        #pragma unroll
        for (int j = 0; j < 4; j++) { o[j] = f2bf(f0[j]); o[j + 4] = f2bf(f1[j]); }
        *(short8*)&xvb[c * 8] = o;
    }
    for (int c = idx; c < CXT; c += stride) {
        float4v f0 = *(const float4v*)&xt[c * 8];
        float4v f1 = *(const float4v*)&xt[c * 8 + 4];
        short8 o;
        #pragma unroll
        for (int j = 0; j < 4; j++) { o[j] = f2bf(f0[j]); o[j + 4] = f2bf(f1[j]); }
        *(short8*)&xtb[c * 8] = o;
    }
    for (int i = idx; i < NW; i += stride) {
        int n = i >> 9;          // output col index
        int k = i & 511;         // contraction dim d
        int h = n >> 6, e = n & 63;
        int src = h * (DMODEL * DHEAD) + k * DHEAD + e;
        wqb[i] = f2bf(wq[src]);
        wkb[i] = f2bf(wk[src]);
        wvb[i] = f2bf(wv[src]);
        wob[i] = f2bf(wo[k * DMODEL + n]);
    }
}

// ---------------------------------------------------------------------------
// Positional encoding value at (row=pos, col)
// ---------------------------------------------------------------------------
static __device__ __forceinline__ float pe_val(int row, int col) {
    int i = col >> 1;
    float freq = expf((float)i * (9.210340371976184f / 512.0f)); // ln(1e4)/512
    float x = (float)row / freq;
    return (col & 1) ? cosf(x) : sinf(x);
}

// ---------------------------------------------------------------------------
// GEMM: C[M][512] = A[M][512] * B^T[512][512]^T, bf16 in, 64x64 tile, BK=64.
// MODE 0: bf16 row-major out. MODE 1: fp32 out + positional encoding.
// MODE 2: bf16 TRANSPOSED out, C_T[col][ldm + row] (for V^T).
// ---------------------------------------------------------------------------
template<int MODE>
__global__ __launch_bounds__(256) void gemm64(const short* __restrict__ A,
                                              const short* __restrict__ BT,
                                              void* __restrict__ Cout, int ldm) {
    __shared__ __align__(16) short As[64][72];   // 64 rows x 64 k (pad 72)
    __shared__ __align__(16) short Bs[64][72];   // 64 cols x 64 k (pad 72)
    int m0 = blockIdx.x * 64;
    int n0 = blockIdx.y * 64;
    int t = threadIdx.x;
    int lane = t & 63, w = t >> 6;
    int wr = w >> 1, wc = w & 1;
    int l15 = lane & 15, g = lane >> 4;

    f32x4 acc[2][2] = {};
    for (int kk = 0; kk < DMODEL; kk += 64) {
        {
            int row = t >> 2, c0 = (t & 3) * 16;
            *(short8*)&As[row][c0]     = *(const short8*)&A[(m0 + row) * DMODEL + kk + c0];
            *(short8*)&As[row][c0 + 8] = *(const short8*)&A[(m0 + row) * DMODEL + kk + c0 + 8];
            *(short8*)&Bs[row][c0]     = *(const short8*)&BT[(n0 + row) * DMODEL + kk + c0];
            *(short8*)&Bs[row][c0 + 8] = *(const short8*)&BT[(n0 + row) * DMODEL + kk + c0 + 8];
        }
        __syncthreads();
        #pragma unroll
        for (int ks = 0; ks < 2; ks++) {
            short8 a[2], b[2];
            #pragma unroll
            for (int fr = 0; fr < 2; fr++) a[fr] = *(short8*)&As[wr * 32 + fr * 16 + l15][ks * 32 + g * 8];
            #pragma unroll
            for (int fc = 0; fc < 2; fc++) b[fc] = *(short8*)&Bs[wc * 32 + fc * 16 + l15][ks * 32 + g * 8];
            #pragma unroll
            for (int fr = 0; fr < 2; fr++)
                #pragma unroll
                for (int fc = 0; fc < 2; fc++)
                    acc[fr][fc] = __builtin_amdgcn_mfma_f32_16x16x32_bf16(a[fr], b[fc], acc[fr][fc], 0, 0, 0);
        }
        __syncthreads();
    }
    #pragma unroll
    for (int fr = 0; fr < 2; fr++)
        #pragma unroll
        for (int fc = 0; fc < 2; fc++)
            #pragma unroll
            for (int r = 0; r < 4; r++) {
                int row = m0 + wr * 32 + fr * 16 + g * 4 + r;
                int col = n0 + wc * 32 + fc * 16 + l15;
                float v = acc[fr][fc][r];
                if (MODE == 1) {
                    ((float*)Cout)[row * DMODEL + col] = v + pe_val(row, col);
                } else if (MODE == 2) {
                    ((short*)Cout)[col * ldm + row] = f2bf(v);
                } else {
                    ((short*)Cout)[row * DMODEL + col] = f2bf(v);
                }
            }
}

// ---------------------------------------------------------------------------
// Attention v2: K and V^T fragments read DIRECTLY from global (L2-resident,
// contiguous 16B per lane). No barriers in the K-loop. Only the wave-private
// P re-layout round-trips through (tiny) LDS.
// Single-pass exp-sum softmax (energies bounded, no max subtraction).
// ---------------------------------------------------------------------------
__global__ __launch_bounds__(256) void attn_kernel(const short* __restrict__ Qb,
                                                   const short* __restrict__ Kb,
                                                   const short* __restrict__ VbT,
                                                   short* __restrict__ Yb) {
    __shared__ __align__(16) short Ps[4][16][40];  // per-wave P tile 16 q x 32 keys

    int h = blockIdx.y;
    int n0 = blockIdx.x * 64;
    int t = threadIdx.x;
    int lane = t & 63, w = t >> 6;
    int l15 = lane & 15, g = lane >> 4;

    // Q fragments direct from global (loop-invariant)
    const short* qrow = Qb + (n0 + w * 16 + l15) * DMODEL + h * DHEAD;
    short8 qa0 = *(const short8*)(qrow + g * 8);
    short8 qa1 = *(const short8*)(qrow + 32 + g * 8);

    const short* Kh = Kb + h * DHEAD;                    // K[m][512]
    const short* Vh = VbT + (h * DHEAD) * M_TOK;         // V^T[d][1024]

    f32x4 acc[4] = {};
    float rsum[4] = {0.f, 0.f, 0.f, 0.f};

    for (int kb = 0; kb < M_TOK; kb += 32) {
        // QK^T: two 16-key subtiles; K fragments straight from global
        #pragma unroll
        for (int kt = 0; kt < 2; kt++) {
            const short* krow = Kh + (kb + kt * 16 + l15) * DMODEL;
            f32x4 e = {};
            short8 kf0 = *(const short8*)(krow + g * 8);
            short8 kf1 = *(const short8*)(krow + 32 + g * 8);
            e = __builtin_amdgcn_mfma_f32_16x16x32_bf16(qa0, kf0, e, 0, 0, 0);
            e = __builtin_amdgcn_mfma_f32_16x16x32_bf16(qa1, kf1, e, 0, 0, 0);
            #pragma unroll
            for (int r = 0; r < 4; r++) {
                float p = expf(e[r]);
                rsum[r] += p;
                Ps[w][g * 4 + r][kt * 16 + l15] = f2bf(p);
            }
        }
        // PV: A = P[16 q x 32 keys] (via LDS re-layout), B = V^T from global
        short8 pa = *(short8*)&Ps[w][l15][g * 8];
        #pragma unroll
        for (int nt = 0; nt < 4; nt++) {
            short8 vf = *(const short8*)(Vh + (nt * 16 + l15) * M_TOK + kb + g * 8);
            acc[nt] = __builtin_amdgcn_mfma_f32_16x16x32_bf16(pa, vf, acc[nt], 0, 0, 0);
        }
    }

    // reduce rsum across the 16 lanes of each row-group
    #pragma unroll
    for (int r = 0; r < 4; r++) {
        float s = rsum[r];
        s += __shfl_xor(s, 1);
        s += __shfl_xor(s, 2);
        s += __shfl_xor(s, 4);
        s += __shfl_xor(s, 8);
        rsum[r] = s;
    }

    // write Y[n][h*64 + e]
    #pragma unroll
    for (int nt = 0; nt < 4; nt++)
        #pragma unroll
        for (int r = 0; r < 4; r++) {
            float y = acc[nt][r] / rsum[r];
            Yb[(n0 + w * 16 + g * 4 + r) * DMODEL + h * DHEAD + nt * 16 + l15] = f2bf(y);
        }
}

// ---------------------------------------------------------------------------
extern "C" void kernel_launch(void* const* d_in, const int* in_sizes, int n_in,
                              void* d_out, int out_size, void* d_ws, size_t ws_size,
                              hipStream_t stream) {
    const float* xv = (const float*)d_in[0];
    const float* xt = (const float*)d_in[1];
    const float* wq = (const float*)d_in[2];
    const float* wk = (const float*)d_in[3];
    const float* wv = (const float*)d_in[4];
    const float* wo = (const float*)d_in[5];

    short* xvb = (short*)d_ws;              // 4096*512
    short* xtb = xvb + N_TOK * DMODEL;      // 1024*512
    short* wqb = xtb + M_TOK * DMODEL;      // 512*512 (B^T)
    short* wkb = wqb + DMODEL * DMODEL;
    short* wvb = wkb + DMODEL * DMODEL;
    short* wob = wvb + DMODEL * DMODEL;
    short* qb  = wob + DMODEL * DMODEL;     // 4096*512
    short* kbm = qb  + N_TOK * DMODEL;      // 1024*512
    short* vbt = kbm + M_TOK * DMODEL;      // 512*1024 (V^T)
    short* yb  = vbt + M_TOK * DMODEL;      // 4096*512

    pack_kernel<<<1024, 256, 0, stream>>>(xv, xt, wq, wk, wv, wo,
                                          xvb, xtb, wqb, wkb, wvb, wob);
    gemm64<0><<<dim3(N_TOK / 64, 8), 256, 0, stream>>>(xvb, wqb, qb, 0);
    gemm64<0><<<dim3(M_TOK / 64, 8), 256, 0, stream>>>(xtb, wkb, kbm, 0);
    gemm64<2><<<dim3(M_TOK / 64, 8), 256, 0, stream>>>(xtb, wvb, vbt, M_TOK);
    attn_kernel<<<dim3(N_TOK / 64, 8), 256, 0, stream>>>(qb, kbm, vbt, yb);
    gemm64<1><<<dim3(N_TOK / 64, 8), 256, 0, stream>>>(yb, wob, d_out, 0);
}